// Round 1
// baseline (11431.418 us; speedup 1.0000x reference)
//
#include <hip/hip_runtime.h>
#include <math.h>

// QRNN forward: embed -> 3x [causal conv1d (GEMM) -> tanh/sig -> fo_pool scan
//               -> LayerNorm -> residual] -> masked maxpool -> 2-layer head.
// fp32 baseline (no fp32 MFMA on CDNA4; conv GEMM runs on vector ALU).

#define B_   16
#define T_   1024
#define H_   1024
#define NL_  3
#define KW   3
#define N3H  3072
#define MTOT (B_ * T_)   // 16384

// ---------------------------------------------------------------- embedding
__global__ __launch_bounds__(256) void embed_kernel(const int* __restrict__ ids,
                                                    const float* __restrict__ emb,
                                                    float* __restrict__ X) {
    const int r = blockIdx.x;              // 0..MTOT-1
    const int id = ids[r];
    const float4* src = (const float4*)(emb + (size_t)id * H_);
    float4* dst = (float4*)(X + (size_t)r * H_);
    dst[threadIdx.x] = src[threadIdx.x];   // 256 thr * 16B = 4KB row
}

// ------------------------------------------------------- conv GEMM (fused act)
// C[r, n] = sum_{kk} sum_i X[r + kk - 2, i] * W[kk, i, n] + bias[n]
// then z=tanh (n<1024), f/o=sigmoid. 128x128 tile, 8x8 per thread, BK=8.
#define BM 128
#define BN 128
#define BK 8

__global__ __launch_bounds__(256) void conv_gemm_kernel(
    const float* __restrict__ X,     // (MTOT, H_)
    const float* __restrict__ W,     // (KW, H_, N3H)
    const float* __restrict__ bias,  // (N3H)
    float* __restrict__ ZFO)         // (MTOT, N3H) activated
{
    __shared__ float As[BK][BM];
    __shared__ float Bs[BK][BN];

    const int tid = threadIdx.x;
    const int m0 = blockIdx.y * BM;
    const int n0 = blockIdx.x * BN;

    const int tn = tid & 15;        // 0..15 (col group)
    const int tm = tid >> 4;        // 0..15 (row group)

    // A staging: thread loads float4 along k for one row
    const int ar = tid >> 1;             // 0..127
    const int ak = (tid & 1) * 4;        // 0 or 4
    // B staging: thread loads float4 along n for one k-row
    const int bk = tid >> 5;             // 0..7
    const int bn = (tid & 31) * 4;       // 0..124

    const int row = m0 + ar;
    const int tt  = row & (T_ - 1);      // t within batch (T_ divides BM grid)

    float acc[8][8];
#pragma unroll
    for (int i = 0; i < 8; ++i)
#pragma unroll
        for (int j = 0; j < 8; ++j) acc[i][j] = 0.f;

    for (int kk = 0; kk < KW; ++kk) {
        const int shift = kk - 2;                  // -2, -1, 0 (causal)
        const bool valid = (tt + shift) >= 0;
        const float* Arow = X + (size_t)(row + shift) * H_;
        const float* Wk = W + (size_t)kk * H_ * N3H;

        for (int k0 = 0; k0 < H_; k0 += BK) {
            float4 av = valid ? *(const float4*)(Arow + k0 + ak)
                              : make_float4(0.f, 0.f, 0.f, 0.f);
            As[ak + 0][ar] = av.x;
            As[ak + 1][ar] = av.y;
            As[ak + 2][ar] = av.z;
            As[ak + 3][ar] = av.w;
            *(float4*)&Bs[bk][bn] =
                *(const float4*)(Wk + (size_t)(k0 + bk) * N3H + n0 + bn);
            __syncthreads();

#pragma unroll
            for (int k = 0; k < BK; ++k) {
                float a[8], b[8];
                *(float4*)&a[0] = *(const float4*)&As[k][tm * 8];
                *(float4*)&a[4] = *(const float4*)&As[k][tm * 8 + 4];
                *(float4*)&b[0] = *(const float4*)&Bs[k][tn * 8];
                *(float4*)&b[4] = *(const float4*)&Bs[k][tn * 8 + 4];
#pragma unroll
                for (int i = 0; i < 8; ++i)
#pragma unroll
                    for (int j = 0; j < 8; ++j)
                        acc[i][j] = fmaf(a[i], b[j], acc[i][j]);
            }
            __syncthreads();
        }
    }

    // epilogue: bias + activation (tile is entirely in one z/f/o region)
    float bias_r[8];
#pragma unroll
    for (int j = 0; j < 8; ++j) bias_r[j] = bias[n0 + tn * 8 + j];
    const int region = n0 >> 10;   // 0:z 1:f 2:o

#pragma unroll
    for (int i = 0; i < 8; ++i) {
        const int r2 = m0 + tm * 8 + i;
        float v[8];
#pragma unroll
        for (int j = 0; j < 8; ++j) {
            float t = acc[i][j] + bias_r[j];
            if (region == 0) t = tanhf(t);
            else             t = 1.f / (1.f + expf(-t));
            v[j] = t;
        }
        float* dst = ZFO + (size_t)r2 * N3H + n0 + tn * 8;
        *(float4*)dst       = make_float4(v[0], v[1], v[2], v[3]);
        *(float4*)(dst + 4) = make_float4(v[4], v[5], v[6], v[7]);
    }
}

// ------------------------------------------------------------------ fo_pool
// h_t = (o_t*f_t) * h_{t-1} + o_t*(1-f_t)*z_t ; h_{-1} = h0
__global__ __launch_bounds__(256) void fo_scan_kernel(const float* __restrict__ ZFO,
                                                      float* __restrict__ Hbuf,
                                                      float* __restrict__ hidden,
                                                      int use_h0) {
    const int id = blockIdx.x * 256 + threadIdx.x;   // 0..16383
    const int b = id >> 10, c = id & 1023;
    float h = use_h0 ? hidden[id] : 0.f;
    const float* base = ZFO + (size_t)b * T_ * N3H + c;
    float* out = Hbuf + (size_t)b * T_ * H_ + c;

    for (int t = 0; t < T_; t += 8) {
        float zv[8], fv[8], ov[8];
#pragma unroll
        for (int u = 0; u < 8; ++u) {
            const float* p = base + (size_t)(t + u) * N3H;
            zv[u] = p[0];
            fv[u] = p[H_];
            ov[u] = p[2 * H_];
        }
#pragma unroll
        for (int u = 0; u < 8; ++u) {
            const float a = ov[u] * fv[u];
            const float bb = ov[u] * (1.f - fv[u]) * zv[u];
            h = fmaf(a, h, bb);
            out[(size_t)(t + u) * H_] = h;
        }
    }
    hidden[id] = h;   // h[:, -1] for next layer
}

// ------------------------------------------------------- LayerNorm + residual
__global__ __launch_bounds__(256) void ln_kernel(const float* __restrict__ Hbuf,
                                                 const float* __restrict__ g,
                                                 const float* __restrict__ be,
                                                 const float* __restrict__ skip,
                                                 float* __restrict__ OutCur,
                                                 float* __restrict__ Xnext,
                                                 int add_skip) {
    __shared__ float red[8];
    const int row = blockIdx.x;
    const int tid = threadIdx.x;

    const float4 v = *(const float4*)(Hbuf + (size_t)row * H_ + tid * 4);
    float s  = v.x + v.y + v.z + v.w;
    float s2 = v.x * v.x + v.y * v.y + v.z * v.z + v.w * v.w;
#pragma unroll
    for (int off = 32; off; off >>= 1) {
        s  += __shfl_down(s, off);
        s2 += __shfl_down(s2, off);
    }
    if ((tid & 63) == 0) { red[tid >> 6] = s; red[4 + (tid >> 6)] = s2; }
    __syncthreads();
    s  = red[0] + red[1] + red[2] + red[3];
    s2 = red[4] + red[5] + red[6] + red[7];

    const float mu  = s * (1.f / 1024.f);
    const float var = s2 * (1.f / 1024.f) - mu * mu;
    const float inv = 1.f / sqrtf(var + 1e-5f);

    const float4 gg = *(const float4*)(g  + tid * 4);
    const float4 bb = *(const float4*)(be + tid * 4);
    float4 o;
    o.x = (v.x - mu) * inv * gg.x + bb.x;
    o.y = (v.y - mu) * inv * gg.y + bb.y;
    o.z = (v.z - mu) * inv * gg.z + bb.z;
    o.w = (v.w - mu) * inv * gg.w + bb.w;
    *(float4*)(OutCur + (size_t)row * H_ + tid * 4) = o;

    float4 xn = o;
    if (add_skip) {
        const float4 sk = *(const float4*)(skip + (size_t)row * H_ + tid * 4);
        xn.x += sk.x; xn.y += sk.y; xn.z += sk.z; xn.w += sk.w;
    }
    *(float4*)(Xnext + (size_t)row * H_ + tid * 4) = xn;
}

// ---------------------------------------------------------------- mask/pool
__global__ __launch_bounds__(256) void lengths_kernel(const int* __restrict__ mask,
                                                      int* __restrict__ lengths) {
    __shared__ int red[4];
    const int b = blockIdx.x, tid = threadIdx.x;
    int s = 0;
    for (int k = tid; k < T_; k += 256) s += mask[b * T_ + k];
#pragma unroll
    for (int off = 32; off; off >>= 1) s += __shfl_down(s, off);
    if ((tid & 63) == 0) red[tid >> 6] = s;
    __syncthreads();
    if (tid == 0) lengths[b] = red[0] + red[1] + red[2] + red[3];
}

__global__ __launch_bounds__(256) void maxpool_kernel(const float* __restrict__ X,
                                                      const int* __restrict__ lengths,
                                                      float* __restrict__ pooled) {
    const int id = blockIdx.x * 256 + threadIdx.x;
    const int b = id >> 10, c = id & 1023;
    const int len = lengths[b];
    const float* p = X + (size_t)b * T_ * H_ + c;
    float m = -INFINITY;
    int t = 0;
    for (; t + 8 <= len; t += 8) {
#pragma unroll
        for (int u = 0; u < 8; ++u) m = fmaxf(m, p[(size_t)(t + u) * H_]);
    }
    for (; t < len; ++t) m = fmaxf(m, p[(size_t)t * H_]);
    pooled[id] = m;
}

// --------------------------------------------------------------------- head
__global__ __launch_bounds__(256) void head1_kernel(const float* __restrict__ pooled,
                                                    const float* __restrict__ W1,
                                                    const float* __restrict__ b1,
                                                    float* __restrict__ h1) {
    const int id = blockIdx.x * 256 + threadIdx.x;   // 0..16383
    const int b = id >> 10, j = id & 1023;
    const float* pb = pooled + b * H_;
    float acc = 0.f;
    for (int i = 0; i < H_; i += 8) {
#pragma unroll
        for (int u = 0; u < 8; ++u)
            acc = fmaf(pb[i + u], W1[(size_t)(i + u) * H_ + j], acc);
    }
    h1[id] = fmaxf(acc + b1[j], 0.f);
}

__global__ __launch_bounds__(256) void head2_kernel(const float* __restrict__ h1,
                                                    const float* __restrict__ W2,
                                                    const float* __restrict__ b2,
                                                    float* __restrict__ out) {
    const int tid = threadIdx.x;          // one block of 256
    const int oi = tid >> 3;              // 0..31 output index
    const int seg = tid & 7;
    const int b = oi >> 1, jo = oi & 1;
    const float* hb = h1 + b * H_;
    float acc = 0.f;
    const int i0 = seg * 128;
    for (int i = i0; i < i0 + 128; ++i)
        acc = fmaf(hb[i], W2[i * 2 + jo], acc);
    acc += __shfl_down(acc, 4);
    acc += __shfl_down(acc, 2);
    acc += __shfl_down(acc, 1);
    if (seg == 0) out[oi] = acc + b2[jo];
}

// ------------------------------------------------------------------- launch
extern "C" void kernel_launch(void* const* d_in, const int* in_sizes, int n_in,
                              void* d_out, int out_size, void* d_ws, size_t ws_size,
                              hipStream_t stream) {
    const int*   input_ids = (const int*)d_in[0];
    const int*   attn_mask = (const int*)d_in[1];
    const float* emb   = (const float*)d_in[2];
    const float* convW = (const float*)d_in[3];
    const float* convb = (const float*)d_in[4];
    const float* gamma = (const float*)d_in[5];
    const float* beta  = (const float*)d_in[6];
    const float* W1    = (const float*)d_in[7];
    const float* b1    = (const float*)d_in[8];
    const float* W2    = (const float*)d_in[9];
    const float* b2    = (const float*)d_in[10];

    float* ws = (float*)d_ws;
    float* Xb     = ws;                                   // MTOT*H
    float* ZFO    = Xb   + (size_t)MTOT * H_;             // MTOT*3H
    float* Hb     = ZFO  + (size_t)MTOT * N3H;            // MTOT*H
    float* Out0   = Hb   + (size_t)MTOT * H_;             // MTOT*H
    float* Out1   = Out0 + (size_t)MTOT * H_;             // MTOT*H
    float* hidden = Out1 + (size_t)MTOT * H_;             // B*H
    float* pooled = hidden + (size_t)B_ * H_;             // B*H
    float* h1     = pooled + (size_t)B_ * H_;             // B*H
    int*   lengths = (int*)(h1 + (size_t)B_ * H_);        // B

    embed_kernel<<<dim3(MTOT), dim3(256), 0, stream>>>(input_ids, emb, Xb);

    const float* skipPrev = nullptr;
    float* outPing[2] = {Out0, Out1};
    for (int l = 0; l < NL_; ++l) {
        const float* Wl = convW + (size_t)l * KW * H_ * N3H;
        conv_gemm_kernel<<<dim3(N3H / BN, MTOT / BM), dim3(256), 0, stream>>>(
            Xb, Wl, convb + (size_t)l * N3H, ZFO);
        fo_scan_kernel<<<dim3(MTOT * /*H per thread*/ 1 / 256 * 1), dim3(256), 0, stream>>>(
            ZFO, Hb, hidden, l > 0 ? 1 : 0);
        float* outCur = outPing[l & 1];
        ln_kernel<<<dim3(MTOT), dim3(256), 0, stream>>>(
            Hb, gamma + (size_t)l * H_, beta + (size_t)l * H_,
            skipPrev, outCur, Xb, l > 0 ? 1 : 0);
        skipPrev = outCur;
    }

    lengths_kernel<<<dim3(B_), dim3(256), 0, stream>>>(attn_mask, lengths);
    maxpool_kernel<<<dim3((B_ * H_) / 256), dim3(256), 0, stream>>>(Xb, lengths, pooled);
    head1_kernel<<<dim3((B_ * H_) / 256), dim3(256), 0, stream>>>(pooled, W1, b1, h1);
    head2_kernel<<<dim3(1), dim3(256), 0, stream>>>(h1, W2, b2, (float*)d_out);
}

// Round 2
// 3709.613 us; speedup vs baseline: 3.0816x; 3.0816x over previous
//
#include <hip/hip_runtime.h>
#include <math.h>

// QRNN forward, round 2: conv GEMM on bf16 MFMA with hi/lo split precision
// (A_hi*B_hi + A_hi*B_lo + A_lo*B_hi, fp32 accumulate). m97-style 128x128
// tile, BK=32, global_load_lds staging, 4 waves, 16x16x32 bf16 MFMA.

#define B_   16
#define T_   1024
#define TP_  1026            // T + 2 zero-pad rows per batch (causal shifts)
#define H_   1024
#define NL_  3
#define KW   3
#define N3H  3072
#define MTOT (B_ * T_)       // 16384
#define BKS  32

typedef __attribute__((ext_vector_type(8))) __bf16 bfrag;     // MFMA A/B frag
typedef __attribute__((ext_vector_type(4))) float f32x4;      // MFMA C/D
typedef __attribute__((ext_vector_type(8))) unsigned short us8;
typedef __attribute__((ext_vector_type(4))) unsigned short us4;

typedef unsigned int __attribute__((address_space(1))) gu32;
typedef unsigned int __attribute__((address_space(3))) lu32;

static __device__ __forceinline__ void gl16(const void* g, void* l) {
    __builtin_amdgcn_global_load_lds((const gu32*)g, (lu32*)l, 16, 0, 0);
}

static __device__ __forceinline__ unsigned short f2bf(float x) {
    unsigned int u = __float_as_uint(x);
    u += 0x7fff + ((u >> 16) & 1);           // round-to-nearest-even
    return (unsigned short)(u >> 16);
}
static __device__ __forceinline__ float bf2f(unsigned short h) {
    return __uint_as_float(((unsigned int)h) << 16);
}

// ------------------------------------------------- embedding gather + split
__global__ __launch_bounds__(128) void embed_split_kernel(
    const int* __restrict__ ids, const float* __restrict__ emb,
    unsigned short* __restrict__ Xh, unsigned short* __restrict__ Xl)
{
    const int tp = blockIdx.x;               // 0..TP_-1
    const int b  = blockIdx.y;               // 0..B_-1
    const int c0 = threadIdx.x * 8;
    const size_t o = ((size_t)b * TP_ + tp) * H_ + c0;
    if (tp < 2) {                            // zero pad rows (causal boundary)
        us8 z = (us8)0;
        *(us8*)(Xh + o) = z; *(us8*)(Xl + o) = z;
        return;
    }
    const int id = ids[b * T_ + tp - 2];
    const float* src = emb + (size_t)id * H_ + c0;
    us8 h, l;
#pragma unroll
    for (int j = 0; j < 8; ++j) {
        float x = src[j];
        unsigned short hh = f2bf(x);
        h[j] = hh;
        l[j] = f2bf(x - bf2f(hh));
    }
    *(us8*)(Xh + o) = h; *(us8*)(Xl + o) = l;
}

// ------------------------------------- W transpose + split: (KW,H,3H)->(KW,3H,H)
__global__ __launch_bounds__(256) void wsplit_kernel(
    const float* __restrict__ W,
    unsigned short* __restrict__ Wh, unsigned short* __restrict__ Wl)
{
    __shared__ float t[32][33];
    const int kk = blockIdx.z;
    const int i0 = blockIdx.y * 32;
    const int n0 = blockIdx.x * 32;
    const int r = threadIdx.x >> 3;
    const int c = (threadIdx.x & 7) * 4;
    const float4 v = *(const float4*)(W + ((size_t)kk * H_ + i0 + r) * N3H + n0 + c);
    t[r][c] = v.x; t[r][c + 1] = v.y; t[r][c + 2] = v.z; t[r][c + 3] = v.w;
    __syncthreads();
    const size_t o = ((size_t)kk * N3H + n0 + r) * H_ + i0 + c;
    us4 h, l;
#pragma unroll
    for (int j = 0; j < 4; ++j) {
        float x = t[c + j][r];
        unsigned short hh = f2bf(x);
        h[j] = hh;
        l[j] = f2bf(x - bf2f(hh));
    }
    *(us4*)(Wh + o) = h; *(us4*)(Wl + o) = l;
}

// ---------------------------------------------- conv GEMM via bf16 MFMA x3
// C[r,n] = sum_kk sum_i X[r+kk-2,i] * W[kk,i,n]; A rows via padded Xp.
// 128x128 tile, BK=32, waves 2x2, each wave 4x4 frags of 16x16x32.
__global__ __launch_bounds__(256, 2) void conv_gemm_mfma(
    const unsigned short* __restrict__ Xh, const unsigned short* __restrict__ Xl,
    const unsigned short* __restrict__ Wh, const unsigned short* __restrict__ Wl,
    const float* __restrict__ bias, float* __restrict__ ZFO)
{
    __shared__ short lds[4][128 * BKS];      // Ah, Al, Bh, Bl (8KB each)

    const int tid  = threadIdx.x;
    const int lane = tid & 63;
    const int w    = tid >> 6;               // wave 0..3
    const int wr   = w >> 1, wc = w & 1;

    // XCD-aware swizzle (3072 % 8 == 0 -> bijective)
    const int nwg = gridDim.x * gridDim.y;
    const int id0 = blockIdx.y * gridDim.x + blockIdx.x;
    const int sw  = (id0 & 7) * (nwg >> 3) + (id0 >> 3);
    const int bx  = sw % 24, by = sw / 24;

    const int m0 = by * 128;
    const int n0 = bx * 128;
    const int batch = m0 >> 10;
    const int t0 = m0 & 1023;

    // staging: chunk ch covers rows ch*16..+15; lane covers row ch*16+lane/4,
    // bytes (lane&3)*16 of the 64B (32 bf16) k-slice. Row stride 2048B for
    // both Xp[.][1024] and Wt[.][1024].
    const int laneoff = ((lane >> 2) * 2048) + ((lane & 3) * 16);
    const char* Xhb = (const char*)Xh + (size_t)(batch * TP_ + t0) * 2048;
    const char* Xlb = (const char*)Xl + (size_t)(batch * TP_ + t0) * 2048;
    const char* Whb = (const char*)Wh + (size_t)n0 * 2048;
    const char* Wlb = (const char*)Wl + (size_t)n0 * 2048;

    f32x4 acc[4][4];
#pragma unroll
    for (int m = 0; m < 4; ++m)
#pragma unroll
        for (int n = 0; n < 4; ++n) acc[m][n] = (f32x4)0.f;

    // frag LDS offsets (shorts): row*BKS + (lane>>4)*8
    const int afr = (wr * 64 + (lane & 15)) * BKS + (lane >> 4) * 8;
    const int bfr = (wc * 64 + (lane & 15)) * BKS + (lane >> 4) * 8;

    for (int kk = 0; kk < KW; ++kk) {
        const char* Akh = Xhb + (size_t)kk * 2048;       // X[b][t0+kk+r]
        const char* Akl = Xlb + (size_t)kk * 2048;
        const char* Bkh = Whb + (size_t)kk * ((size_t)N3H * 2048);
        const char* Bkl = Wlb + (size_t)kk * ((size_t)N3H * 2048);

        for (int k0 = 0; k0 < H_; k0 += BKS) {
            const int kb = k0 * 2;
            __syncthreads();                 // protect LDS from prev iter readers
#pragma unroll
            for (int i = 0; i < 2; ++i) {
                const int ch = i * 4 + w;    // chunk 0..7 (wave-uniform)
                const size_t go = (size_t)ch * 32768 + kb + laneoff;
                gl16(Akh + go, &lds[0][ch * 512]);
                gl16(Akl + go, &lds[1][ch * 512]);
                gl16(Bkh + go, &lds[2][ch * 512]);
                gl16(Bkl + go, &lds[3][ch * 512]);
            }
            __syncthreads();                 // vmcnt(0) drain + barrier

            bfrag ah[4], al[4], bh[4], bl[4];
#pragma unroll
            for (int m = 0; m < 4; ++m) {
                ah[m] = *(const bfrag*)&lds[0][afr + m * 16 * BKS];
                al[m] = *(const bfrag*)&lds[1][afr + m * 16 * BKS];
                bh[m] = *(const bfrag*)&lds[2][bfr + m * 16 * BKS];
                bl[m] = *(const bfrag*)&lds[3][bfr + m * 16 * BKS];
            }
#pragma unroll
            for (int m = 0; m < 4; ++m)
#pragma unroll
                for (int n = 0; n < 4; ++n)
                    acc[m][n] = __builtin_amdgcn_mfma_f32_16x16x32_bf16(ah[m], bh[n], acc[m][n], 0, 0, 0);
#pragma unroll
            for (int m = 0; m < 4; ++m)
#pragma unroll
                for (int n = 0; n < 4; ++n)
                    acc[m][n] = __builtin_amdgcn_mfma_f32_16x16x32_bf16(ah[m], bl[n], acc[m][n], 0, 0, 0);
#pragma unroll
            for (int m = 0; m < 4; ++m)
#pragma unroll
                for (int n = 0; n < 4; ++n)
                    acc[m][n] = __builtin_amdgcn_mfma_f32_16x16x32_bf16(al[m], bh[n], acc[m][n], 0, 0, 0);
        }
    }

    // epilogue: bias + activation; C/D layout col=lane&15, row=(lane>>4)*4+j
    const int region = n0 >> 10;             // 0:z(tanh) 1:f 2:o (sigmoid)
    const int lcol = lane & 15;
    const int lrow = (lane >> 4) * 4;
#pragma unroll
    for (int n = 0; n < 4; ++n) {
        const int col = n0 + wc * 64 + n * 16 + lcol;
        const float bs = bias[col];
#pragma unroll
        for (int m = 0; m < 4; ++m) {
            const int row = m0 + wr * 64 + m * 16 + lrow;
#pragma unroll
            for (int j = 0; j < 4; ++j) {
                float v = acc[m][n][j] + bs;
                v = (region == 0) ? tanhf(v) : (1.f / (1.f + expf(-v)));
                ZFO[(size_t)(row + j) * N3H + col] = v;
            }
        }
    }
}

// ------------------------------------------------ fo_pool (in-place: h -> z-slot)
__global__ __launch_bounds__(256) void fo_scan_kernel(float* __restrict__ ZFO,
                                                      float* __restrict__ hidden,
                                                      int use_h0)
{
    const int id = blockIdx.x * 256 + threadIdx.x;   // 0..16383
    const int b = id >> 10, c = id & 1023;
    float h = use_h0 ? hidden[id] : 0.f;
    float* base = ZFO + (size_t)b * T_ * N3H + c;
    for (int t = 0; t < T_; t += 8) {
        float zv[8], fv[8], ov[8];
#pragma unroll
        for (int u = 0; u < 8; ++u) {
            float* p = base + (size_t)(t + u) * N3H;
            zv[u] = p[0]; fv[u] = p[H_]; ov[u] = p[2 * H_];
        }
#pragma unroll
        for (int u = 0; u < 8; ++u) {
            const float a  = ov[u] * fv[u];
            const float bb = ov[u] * (1.f - fv[u]) * zv[u];
            h = fmaf(a, h, bb);
            base[(size_t)(t + u) * N3H] = h;        // overwrite consumed z
        }
    }
    hidden[id] = h;
}

// ---------------------- LayerNorm + residual; emits fp32 x (f-slot) + split X
__global__ __launch_bounds__(256) void ln_kernel(
    const float* __restrict__ Hs,        // h in ZFO z-slot, row stride N3H
    const float* __restrict__ g, const float* __restrict__ be,
    const float* __restrict__ skip,      // prev LN out (fp32, stride H_) or null
    float* __restrict__ OutCur,          // this LN out (fp32, stride H_)
    float* __restrict__ Xfin,            // x_next fp32 -> ZFO f-slot, stride N3H
    unsigned short* __restrict__ Xh, unsigned short* __restrict__ Xl,
    int add_skip)
{
    __shared__ float red[8];
    const int row = blockIdx.x;
    const int tid = threadIdx.x;

    const float4 v = *(const float4*)(Hs + (size_t)row * N3H + tid * 4);
    float s  = v.x + v.y + v.z + v.w;
    float s2 = v.x * v.x + v.y * v.y + v.z * v.z + v.w * v.w;
#pragma unroll
    for (int off = 32; off; off >>= 1) {
        s  += __shfl_down(s, off);
        s2 += __shfl_down(s2, off);
    }
    if ((tid & 63) == 0) { red[tid >> 6] = s; red[4 + (tid >> 6)] = s2; }
    __syncthreads();
    s  = red[0] + red[1] + red[2] + red[3];
    s2 = red[4] + red[5] + red[6] + red[7];

    const float mu  = s * (1.f / 1024.f);
    const float var = s2 * (1.f / 1024.f) - mu * mu;
    const float inv = 1.f / sqrtf(var + 1e-5f);

    const float4 gg = *(const float4*)(g  + tid * 4);
    const float4 bb = *(const float4*)(be + tid * 4);
    float4 o;
    o.x = (v.x - mu) * inv * gg.x + bb.x;
    o.y = (v.y - mu) * inv * gg.y + bb.y;
    o.z = (v.z - mu) * inv * gg.z + bb.z;
    o.w = (v.w - mu) * inv * gg.w + bb.w;
    *(float4*)(OutCur + (size_t)row * H_ + tid * 4) = o;

    float4 xn = o;
    if (add_skip) {
        const float4 sk = *(const float4*)(skip + (size_t)row * H_ + tid * 4);
        xn.x += sk.x; xn.y += sk.y; xn.z += sk.z; xn.w += sk.w;
    }
    *(float4*)(Xfin + (size_t)row * N3H + tid * 4) = xn;

    // split-bf16 X for next layer's MFMA GEMM (padded layout)
    const int b = row >> 10, t = row & 1023;
    const size_t xo = ((size_t)(b * TP_ + t + 2)) * H_ + tid * 4;
    const float xv[4] = {xn.x, xn.y, xn.z, xn.w};
    us4 hh, ll;
#pragma unroll
    for (int j = 0; j < 4; ++j) {
        unsigned short hb = f2bf(xv[j]);
        hh[j] = hb;
        ll[j] = f2bf(xv[j] - bf2f(hb));
    }
    *(us4*)(Xh + xo) = hh; *(us4*)(Xl + xo) = ll;
}

// ---------------------------------------------------------------- mask/pool
__global__ __launch_bounds__(256) void lengths_kernel(const int* __restrict__ mask,
                                                      int* __restrict__ lengths) {
    __shared__ int red[4];
    const int b = blockIdx.x, tid = threadIdx.x;
    int s = 0;
    for (int k = tid; k < T_; k += 256) s += mask[b * T_ + k];
#pragma unroll
    for (int off = 32; off; off >>= 1) s += __shfl_down(s, off);
    if ((tid & 63) == 0) red[tid >> 6] = s;
    __syncthreads();
    if (tid == 0) lengths[b] = red[0] + red[1] + red[2] + red[3];
}

__global__ __launch_bounds__(256) void maxpool_kernel(const float* __restrict__ Xfin,
                                                      const int* __restrict__ lengths,
                                                      float* __restrict__ pooled) {
    const int id = blockIdx.x * 256 + threadIdx.x;
    const int b = id >> 10, c = id & 1023;
    const int len = lengths[b];
    const float* p = Xfin + (size_t)b * T_ * N3H + c;
    float m = -INFINITY;
    int t = 0;
    for (; t + 8 <= len; t += 8) {
#pragma unroll
        for (int u = 0; u < 8; ++u) m = fmaxf(m, p[(size_t)(t + u) * N3H]);
    }
    for (; t < len; ++t) m = fmaxf(m, p[(size_t)t * N3H]);
    pooled[id] = m;
}

// --------------------------------------------------------------------- head
__global__ __launch_bounds__(256) void head1_kernel(const float* __restrict__ pooled,
                                                    const float* __restrict__ W1,
                                                    const float* __restrict__ b1,
                                                    float* __restrict__ h1) {
    const int id = blockIdx.x * 256 + threadIdx.x;
    const int b = id >> 10, j = id & 1023;
    const float* pb = pooled + b * H_;
    float acc = 0.f;
    for (int i = 0; i < H_; i += 8) {
#pragma unroll
        for (int u = 0; u < 8; ++u)
            acc = fmaf(pb[i + u], W1[(size_t)(i + u) * H_ + j], acc);
    }
    h1[id] = fmaxf(acc + b1[j], 0.f);
}

__global__ __launch_bounds__(256) void head2_kernel(const float* __restrict__ h1,
                                                    const float* __restrict__ W2,
                                                    const float* __restrict__ b2,
                                                    float* __restrict__ out) {
    const int tid = threadIdx.x;
    const int oi = tid >> 3;
    const int seg = tid & 7;
    const int b = oi >> 1, jo = oi & 1;
    const float* hb = h1 + b * H_;
    float acc = 0.f;
    const int i0 = seg * 128;
    for (int i = i0; i < i0 + 128; ++i)
        acc = fmaf(hb[i], W2[i * 2 + jo], acc);
    acc += __shfl_down(acc, 4);
    acc += __shfl_down(acc, 2);
    acc += __shfl_down(acc, 1);
    if (seg == 0) out[oi] = acc + b2[jo];
}

// ------------------------------------------------------------------- launch
extern "C" void kernel_launch(void* const* d_in, const int* in_sizes, int n_in,
                              void* d_out, int out_size, void* d_ws, size_t ws_size,
                              hipStream_t stream) {
    const int*   input_ids = (const int*)d_in[0];
    const int*   attn_mask = (const int*)d_in[1];
    const float* emb   = (const float*)d_in[2];
    const float* convW = (const float*)d_in[3];
    const float* convb = (const float*)d_in[4];
    const float* gamma = (const float*)d_in[5];
    const float* beta  = (const float*)d_in[6];
    const float* W1    = (const float*)d_in[7];
    const float* b1    = (const float*)d_in[8];
    const float* W2    = (const float*)d_in[9];
    const float* b2    = (const float*)d_in[10];

    // workspace layout (~441 MB)
    float* ZFO  = (float*)d_ws;                                  // MTOT*N3H f32
    float* Out0 = ZFO  + (size_t)MTOT * N3H;                     // MTOT*H f32
    float* Out1 = Out0 + (size_t)MTOT * H_;                      // MTOT*H f32
    unsigned short* Xh = (unsigned short*)(Out1 + (size_t)MTOT * H_);  // B*TP*H bf16
    unsigned short* Xl = Xh + (size_t)B_ * TP_ * H_;
    unsigned short* Wh = Xl + (size_t)B_ * TP_ * H_;             // KW*N3H*H bf16
    unsigned short* Wl = Wh + (size_t)KW * N3H * H_;
    float* hidden  = (float*)(Wl + (size_t)KW * N3H * H_);       // B*H
    float* pooled  = hidden + (size_t)B_ * H_;
    float* h1      = pooled + (size_t)B_ * H_;
    int*   lengths = (int*)(h1 + (size_t)B_ * H_);

    embed_split_kernel<<<dim3(TP_, B_), 128, 0, stream>>>(input_ids, emb, Xh, Xl);

    const float* skipPrev = nullptr;
    float* outs[2] = {Out0, Out1};
    for (int l = 0; l < NL_; ++l) {
        wsplit_kernel<<<dim3(N3H / 32, H_ / 32, KW), 256, 0, stream>>>(
            convW + (size_t)l * KW * H_ * N3H, Wh, Wl);
        conv_gemm_mfma<<<dim3(N3H / 128, MTOT / 128), 256, 0, stream>>>(
            Xh, Xl, Wh, Wl, convb + (size_t)l * N3H, ZFO);
        fo_scan_kernel<<<dim3(64), dim3(256), 0, stream>>>(ZFO, hidden, l > 0 ? 1 : 0);
        ln_kernel<<<dim3(MTOT), dim3(256), 0, stream>>>(
            ZFO, gamma + (size_t)l * H_, beta + (size_t)l * H_,
            skipPrev, outs[l & 1], ZFO + H_, Xh, Xl, l > 0 ? 1 : 0);
        skipPrev = outs[l & 1];
    }

    lengths_kernel<<<dim3(B_), dim3(256), 0, stream>>>(attn_mask, lengths);
    maxpool_kernel<<<dim3(64), dim3(256), 0, stream>>>(ZFO + H_, lengths, pooled);
    head1_kernel<<<dim3(64), dim3(256), 0, stream>>>(pooled, W1, b1, h1);
    head2_kernel<<<dim3(1), dim3(256), 0, stream>>>(h1, W2, b2, (float*)d_out);
}

// Round 6
// 3119.868 us; speedup vs baseline: 3.6641x; 1.1890x over previous
//
#include <hip/hip_runtime.h>
#include <math.h>

// QRNN forward, round 3 schedule (resubmit x3; rounds 3-5 died at GPU
// acquisition, kernel never executed): conv GEMM -> 256x256 schedule
// (T2 XOR-swizzled LDS + raw-barrier 4-phase K-steps + early-issued
// global_load_lds with single per-step vmcnt + setprio around MFMA).
// Numerics: bf16 hi/lo 3-product, fp32 accum.

#define B_   16
#define T_   1024
#define TP_  1026            // T + 2 zero-pad rows per batch (causal taps)
#define H_   1024
#define NL_  3
#define KW   3
#define N3H  3072
#define MTOT (B_ * T_)       // 16384
#define NSTEP 96             // KW * (H_/32)

// Global hi/lo-interleaved layout ("HL"): row stride 4096 B;
// k-group G (32 k) at G*128: [hi 32xbf16 (64B) | lo 32xbf16 (64B)].

typedef __attribute__((ext_vector_type(8))) __bf16 bfrag;     // MFMA A/B frag
typedef __attribute__((ext_vector_type(4))) float f32x4;      // MFMA C/D
typedef __attribute__((ext_vector_type(8))) unsigned short us8;
typedef __attribute__((ext_vector_type(4))) unsigned short us4;

typedef unsigned int __attribute__((address_space(1))) gu32;
typedef unsigned int __attribute__((address_space(3))) lu32;

static __device__ __forceinline__ void gl16(const void* g, void* l) {
    __builtin_amdgcn_global_load_lds((const gu32*)g, (lu32*)l, 16, 0, 0);
}
static __device__ __forceinline__ unsigned short f2bf(float x) {
    unsigned int u = __float_as_uint(x);
    u += 0x7fff + ((u >> 16) & 1);
    return (unsigned short)(u >> 16);
}
static __device__ __forceinline__ float bf2f(unsigned short h) {
    return __uint_as_float(((unsigned int)h) << 16);
}

// ------------------------------------------------- embedding gather + split
__global__ __launch_bounds__(128) void embed_split_kernel(
    const int* __restrict__ ids, const float* __restrict__ emb,
    char* __restrict__ XHL)
{
    const int tp = blockIdx.x;               // 0..TP_-1
    const int b  = blockIdx.y;
    const int tid = threadIdx.x;             // 0..127, 8 k each
    const int c0 = tid * 8;
    char* row = XHL + (size_t)(b * TP_ + tp) * 4096;
    char* hip_ = row + (tid >> 2) * 128 + (tid & 3) * 16;  // G = tid>>2
    if (tp < 2) {
        *(us8*)hip_ = (us8)0;
        *(us8*)(hip_ + 64) = (us8)0;
        return;
    }
    const int id = ids[b * T_ + tp - 2];
    const float* src = emb + (size_t)id * H_ + c0;
    us8 h, l;
#pragma unroll
    for (int j = 0; j < 8; ++j) {
        float x = src[j];
        unsigned short hh = f2bf(x);
        h[j] = hh;
        l[j] = f2bf(x - bf2f(hh));
    }
    *(us8*)hip_ = h;
    *(us8*)(hip_ + 64) = l;
}

// --------------------- W transpose + split: (KW,H,3H) -> HL[(KW,3H) rows][H]
__global__ __launch_bounds__(256) void wsplit_kernel(
    const float* __restrict__ W, char* __restrict__ WHL)
{
    __shared__ float t[32][33];
    const int kk = blockIdx.z;
    const int i0 = blockIdx.y * 32;          // k tile
    const int n0 = blockIdx.x * 32;          // n tile
    const int r = threadIdx.x >> 3;
    const int c = (threadIdx.x & 7) * 4;
    const float4 v = *(const float4*)(W + ((size_t)kk * H_ + i0 + r) * N3H + n0 + c);
    t[r][c] = v.x; t[r][c + 1] = v.y; t[r][c + 2] = v.z; t[r][c + 3] = v.w;
    __syncthreads();
    // out row = kk*N3H + n0 + r; group G = i0>>5; within-group k = c..c+3
    char* out = WHL + (size_t)(kk * N3H + n0 + r) * 4096 + (i0 >> 5) * 128 + c * 2;
    us4 h, l;
#pragma unroll
    for (int j = 0; j < 4; ++j) {
        float x = t[c + j][r];
        unsigned short hh = f2bf(x);
        h[j] = hh;
        l[j] = f2bf(x - bf2f(hh));
    }
    *(us4*)out = h;
    *(us4*)(out + 64) = l;
}

// --------------------------- conv GEMM, 256x256 tile, 4-phase raw-barrier loop
__global__ __launch_bounds__(512, 2) void conv_gemm_8ph(
    const char* __restrict__ XHL, const char* __restrict__ WHL,
    const float* __restrict__ bias, float* __restrict__ ZFO)
{
    extern __shared__ char lds[];            // 2 bufs x (A 32KB | B 32KB)

    const int tid = threadIdx.x, lane = tid & 63, w = tid >> 6;
    const int wr = w >> 2, wc = w & 3;       // 2 x 4 waves

    // bijective XCD swizzle: nwg = 768 = 8 * 96
    const int id0 = blockIdx.y * gridDim.x + blockIdx.x;
    const int sw  = (id0 & 7) * 96 + (id0 >> 3);
    const int bx = sw % 12, by = sw / 12;
    const int m0 = by * 256, n0 = bx * 256;
    const int batch = m0 >> 10, t0 = m0 & 1023;

    // staging: thread covers LDS row (j*64 + tid>>3), chunk tid&7;
    // source chunk = dest chunk ^ (row&7), row&7 == (tid>>3)&7.
    const int rtid = tid >> 3;
    const int swz  = ((lane & 7) ^ (lane >> 3)) << 4;
    const char* Abase = XHL + (size_t)(batch * TP_ + t0) * 4096;

    // ds_read swizzled chunk offsets (read row&7 == lane&7)
    const int hsw = (((lane >> 4)) ^ (lane & 7)) << 4;
    const int lsw = (((lane >> 4) | 4) ^ (lane & 7)) << 4;
    const int arow = (wr * 128 + (lane & 15)) << 7;            // byte, A tile
    const int brow = ((wc * 64 + (lane & 15)) << 7) + 32768;   // byte, B tile

    f32x4 acc[8][4];
#pragma unroll
    for (int m = 0; m < 8; ++m)
#pragma unroll
        for (int n = 0; n < 4; ++n) acc[m][n] = (f32x4)0.f;

    // ---- staging helpers (4 x gl16 each: 64 rows x 128B per issue) ----
#define STAGE_A(bufb, kk, G)                                                  \
    {                                                                         \
        char* ldst = lds + ((bufb) << 16);                                    \
        const char* src = Abase + (size_t)((kk) + rtid) * 4096 + (G) * 128 + swz; \
        _Pragma("unroll")                                                     \
        for (int j = 0; j < 4; ++j)                                           \
            gl16(src + (size_t)j * (64 * 4096), ldst + j * 8192 + tid * 16);  \
    }
#define STAGE_B(bufb, kk, G)                                                  \
    {                                                                         \
        char* ldst = lds + ((bufb) << 16) + 32768;                            \
        const char* src = WHL + (size_t)((kk) * N3H + n0 + rtid) * 4096 + (G) * 128 + swz; \
        _Pragma("unroll")                                                     \
        for (int j = 0; j < 4; ++j)                                           \
            gl16(src + (size_t)j * (64 * 4096), ldst + j * 8192 + tid * 16);  \
    }

    // prologue: stage step 0
    STAGE_A(0, 0, 0);
    STAGE_B(0, 0, 0);
    asm volatile("s_waitcnt vmcnt(0)" ::: "memory");
    __builtin_amdgcn_s_barrier();

    for (int t = 0; t < NSTEP; ++t) {
        const int buf = t & 1;
        const char* L = lds + (buf << 16);
        const int tn = t + 1;
        const int kkn = tn >> 5, Gn = tn & 31;
        const bool more = (t < NSTEP - 1);

#pragma unroll
        for (int p = 0; p < 4; ++p) {
            const int mh = p >> 1, nh = p & 1;
            bfrag ah[4], al[4], bh[2], bl[2];
#pragma unroll
            for (int m = 0; m < 4; ++m) {
                const int ro = arow + ((mh * 4 + m) << 11);
                ah[m] = *(const bfrag*)(L + ro + hsw);
                al[m] = *(const bfrag*)(L + ro + lsw);
            }
#pragma unroll
            for (int n = 0; n < 2; ++n) {
                const int ro = brow + ((nh * 2 + n) << 11);
                bh[n] = *(const bfrag*)(L + ro + hsw);
                bl[n] = *(const bfrag*)(L + ro + lsw);
            }
            if (more && p == 0) STAGE_A(buf ^ 1, kkn, Gn);
            if (more && p == 1) STAGE_B(buf ^ 1, kkn, Gn);

            __builtin_amdgcn_s_barrier();
            asm volatile("s_waitcnt lgkmcnt(0)" ::: "memory");
            __builtin_amdgcn_sched_barrier(0);
            __builtin_amdgcn_s_setprio(1);
#pragma unroll
            for (int m = 0; m < 4; ++m)
#pragma unroll
                for (int n = 0; n < 2; ++n) {
                    f32x4 a0 = acc[mh * 4 + m][nh * 2 + n];
                    a0 = __builtin_amdgcn_mfma_f32_16x16x32_bf16(ah[m], bh[n], a0, 0, 0, 0);
                    a0 = __builtin_amdgcn_mfma_f32_16x16x32_bf16(ah[m], bl[n], a0, 0, 0, 0);
                    a0 = __builtin_amdgcn_mfma_f32_16x16x32_bf16(al[m], bh[n], a0, 0, 0, 0);
                    acc[mh * 4 + m][nh * 2 + n] = a0;
                }
            __builtin_amdgcn_s_setprio(0);
            __builtin_amdgcn_sched_barrier(0);
            if (p == 3) asm volatile("s_waitcnt vmcnt(0)" ::: "memory");
            __builtin_amdgcn_s_barrier();
        }
    }

    // epilogue: bias + activation, direct stores
    const int lcol = lane & 15, lrow = (lane >> 4) * 4;
#pragma unroll
    for (int n4 = 0; n4 < 4; ++n4) {
        const int col = n0 + wc * 64 + n4 * 16 + lcol;
        const float bs = bias[col];
        const int region = col >> 10;        // uniform across the 16 cols
#pragma unroll
        for (int m = 0; m < 8; ++m) {
            const int row = m0 + wr * 128 + m * 16 + lrow;
#pragma unroll
            for (int j = 0; j < 4; ++j) {
                float v = acc[m][n4][j] + bs;
                v = (region == 0) ? tanhf(v) : (1.f / (1.f + expf(-v)));
                ZFO[(size_t)(row + j) * N3H + col] = v;
            }
        }
    }
#undef STAGE_A
#undef STAGE_B
}

// ------------------------------------------------ fo_pool (in-place: h -> z-slot)
__global__ __launch_bounds__(256) void fo_scan_kernel(float* __restrict__ ZFO,
                                                      float* __restrict__ hidden,
                                                      int use_h0)
{
    const int id = blockIdx.x * 256 + threadIdx.x;   // 0..16383
    const int b = id >> 10, c = id & 1023;
    float h = use_h0 ? hidden[id] : 0.f;
    float* base = ZFO + (size_t)b * T_ * N3H + c;
    for (int t = 0; t < T_; t += 8) {
        float zv[8], fv[8], ov[8];
#pragma unroll
        for (int u = 0; u < 8; ++u) {
            float* p = base + (size_t)(t + u) * N3H;
            zv[u] = p[0]; fv[u] = p[H_]; ov[u] = p[2 * H_];
        }
#pragma unroll
        for (int u = 0; u < 8; ++u) {
            const float a  = ov[u] * fv[u];
            const float bb = ov[u] * (1.f - fv[u]) * zv[u];
            h = fmaf(a, h, bb);
            base[(size_t)(t + u) * N3H] = h;
        }
    }
    hidden[id] = h;
}

// ---------------------- LayerNorm + residual; emits fp32 x (f-slot) + HL X
__global__ __launch_bounds__(256) void ln_kernel(
    const float* __restrict__ Hs,        // h in ZFO z-slot, row stride N3H
    const float* __restrict__ g, const float* __restrict__ be,
    const float* __restrict__ skip,
    float* __restrict__ OutCur,          // LN out (fp32, stride H_)
    float* __restrict__ Xfin,            // x_next fp32 -> ZFO f-slot
    char* __restrict__ XHL,
    int add_skip)
{
    __shared__ float red[8];
    const int row = blockIdx.x;
    const int tid = threadIdx.x;

    const float4 v = *(const float4*)(Hs + (size_t)row * N3H + tid * 4);
    float s  = v.x + v.y + v.z + v.w;
    float s2 = v.x * v.x + v.y * v.y + v.z * v.z + v.w * v.w;
#pragma unroll
    for (int off = 32; off; off >>= 1) {
        s  += __shfl_down(s, off);
        s2 += __shfl_down(s2, off);
    }
    if ((tid & 63) == 0) { red[tid >> 6] = s; red[4 + (tid >> 6)] = s2; }
    __syncthreads();
    s  = red[0] + red[1] + red[2] + red[3];
    s2 = red[4] + red[5] + red[6] + red[7];

    const float mu  = s * (1.f / 1024.f);
    const float var = s2 * (1.f / 1024.f) - mu * mu;
    const float inv = 1.f / sqrtf(var + 1e-5f);

    const float4 gg = *(const float4*)(g  + tid * 4);
    const float4 bb = *(const float4*)(be + tid * 4);
    float4 o;
    o.x = (v.x - mu) * inv * gg.x + bb.x;
    o.y = (v.y - mu) * inv * gg.y + bb.y;
    o.z = (v.z - mu) * inv * gg.z + bb.z;
    o.w = (v.w - mu) * inv * gg.w + bb.w;
    *(float4*)(OutCur + (size_t)row * H_ + tid * 4) = o;

    float4 xn = o;
    if (add_skip) {
        const float4 sk = *(const float4*)(skip + (size_t)row * H_ + tid * 4);
        xn.x += sk.x; xn.y += sk.y; xn.z += sk.z; xn.w += sk.w;
    }
    *(float4*)(Xfin + (size_t)row * N3H + tid * 4) = xn;

    // split-bf16 X (HL layout) for next layer's GEMM
    const int b = row >> 10, t = row & 1023;
    char* xrow = XHL + (size_t)(b * TP_ + t + 2) * 4096
               + (tid >> 3) * 128 + (tid & 7) * 8;   // G = tid>>3, k off = (tid&7)*4
    const float xv[4] = {xn.x, xn.y, xn.z, xn.w};
    us4 hh, ll;
#pragma unroll
    for (int j = 0; j < 4; ++j) {
        unsigned short hb = f2bf(xv[j]);
        hh[j] = hb;
        ll[j] = f2bf(xv[j] - bf2f(hb));
    }
    *(us4*)xrow = hh;
    *(us4*)(xrow + 64) = ll;
}

// ---------------------------------------------------------------- mask/pool
__global__ __launch_bounds__(256) void lengths_kernel(const int* __restrict__ mask,
                                                      int* __restrict__ lengths) {
    __shared__ int red[4];
    const int b = blockIdx.x, tid = threadIdx.x;
    int s = 0;
    for (int k = tid; k < T_; k += 256) s += mask[b * T_ + k];
#pragma unroll
    for (int off = 32; off; off >>= 1) s += __shfl_down(s, off);
    if ((tid & 63) == 0) red[tid >> 6] = s;
    __syncthreads();
    if (tid == 0) lengths[b] = red[0] + red[1] + red[2] + red[3];
}

__global__ __launch_bounds__(256) void maxpool_kernel(const float* __restrict__ Xfin,
                                                      const int* __restrict__ lengths,
                                                      float* __restrict__ pooled) {
    const int id = blockIdx.x * 256 + threadIdx.x;
    const int b = id >> 10, c = id & 1023;
    const int len = lengths[b];
    const float* p = Xfin + (size_t)b * T_ * N3H + c;
    float m = -INFINITY;
    int t = 0;
    for (; t + 8 <= len; t += 8) {
#pragma unroll
        for (int u = 0; u < 8; ++u) m = fmaxf(m, p[(size_t)(t + u) * N3H]);
    }
    for (; t < len; ++t) m = fmaxf(m, p[(size_t)t * N3H]);
    pooled[id] = m;
}

// --------------------------------------------------------------------- head
__global__ __launch_bounds__(256) void head1_kernel(const float* __restrict__ pooled,
                                                    const float* __restrict__ W1,
                                                    const float* __restrict__ b1,
                                                    float* __restrict__ h1) {
    const int id = blockIdx.x * 256 + threadIdx.x;
    const int b = id >> 10, j = id & 1023;
    const float* pb = pooled + b * H_;
    float acc = 0.f;
    for (int i = 0; i < H_; i += 8) {
#pragma unroll
        for (int u = 0; u < 8; ++u)
            acc = fmaf(pb[i + u], W1[(size_t)(i + u) * H_ + j], acc);
    }
    h1[id] = fmaxf(acc + b1[j], 0.f);
}

__global__ __launch_bounds__(256) void head2_kernel(const float* __restrict__ h1,
                                                    const float* __restrict__ W2,
                                                    const float* __restrict__ b2,
                                                    float* __restrict__ out) {
    const int tid = threadIdx.x;
    const int oi = tid >> 3;
    const int seg = tid & 7;
    const int b = oi >> 1, jo = oi & 1;
    const float* hb = h1 + b * H_;
    float acc = 0.f;
    const int i0 = seg * 128;
    for (int i = i0; i < i0 + 128; ++i)
        acc = fmaf(hb[i], W2[i * 2 + jo], acc);
    acc += __shfl_down(acc, 4);
    acc += __shfl_down(acc, 2);
    acc += __shfl_down(acc, 1);
    if (seg == 0) out[oi] = acc + b2[jo];
}

// ------------------------------------------------------------------- launch
extern "C" void kernel_launch(void* const* d_in, const int* in_sizes, int n_in,
                              void* d_out, int out_size, void* d_ws, size_t ws_size,
                              hipStream_t stream) {
    const int*   input_ids = (const int*)d_in[0];
    const int*   attn_mask = (const int*)d_in[1];
    const float* emb   = (const float*)d_in[2];
    const float* convW = (const float*)d_in[3];
    const float* convb = (const float*)d_in[4];
    const float* gamma = (const float*)d_in[5];
    const float* beta  = (const float*)d_in[6];
    const float* W1    = (const float*)d_in[7];
    const float* b1    = (const float*)d_in[8];
    const float* W2    = (const float*)d_in[9];
    const float* b2    = (const float*)d_in[10];

    // workspace (~441 MB, same as round 2)
    float* ZFO  = (float*)d_ws;                                  // MTOT*N3H f32
    float* Out0 = ZFO  + (size_t)MTOT * N3H;
    float* Out1 = Out0 + (size_t)MTOT * H_;
    char*  XHL  = (char*)(Out1 + (size_t)MTOT * H_);             // B*TP*4096 B
    char*  WHL  = XHL + (size_t)B_ * TP_ * 4096;                 // KW*N3H*4096 B
    float* hidden  = (float*)(WHL + (size_t)KW * N3H * 4096);
    float* pooled  = hidden + (size_t)B_ * H_;
    float* h1      = pooled + (size_t)B_ * H_;
    int*   lengths = (int*)(h1 + (size_t)B_ * H_);

    hipFuncSetAttribute((const void*)conv_gemm_8ph,
                        hipFuncAttributeMaxDynamicSharedMemorySize, 131072);

    embed_split_kernel<<<dim3(TP_, B_), 128, 0, stream>>>(input_ids, emb, XHL);

    const float* skipPrev = nullptr;
    float* outs[2] = {Out0, Out1};
    for (int l = 0; l < NL_; ++l) {
        wsplit_kernel<<<dim3(N3H / 32, H_ / 32, KW), 256, 0, stream>>>(
            convW + (size_t)l * KW * H_ * N3H, WHL);
        conv_gemm_8ph<<<dim3(12, 64), 512, 131072, stream>>>(
            XHL, WHL, convb + (size_t)l * N3H, ZFO);
        fo_scan_kernel<<<dim3(64), dim3(256), 0, stream>>>(ZFO, hidden, l > 0 ? 1 : 0);
        ln_kernel<<<dim3(MTOT), dim3(256), 0, stream>>>(
            ZFO, gamma + (size_t)l * H_, beta + (size_t)l * H_,
            skipPrev, outs[l & 1], ZFO + H_, XHL, l > 0 ? 1 : 0);
        skipPrev = outs[l & 1];
    }

    lengths_kernel<<<dim3(B_), dim3(256), 0, stream>>>(attn_mask, lengths);
    maxpool_kernel<<<dim3(64), dim3(256), 0, stream>>>(ZFO + H_, lengths, pooled);
    head1_kernel<<<dim3(64), dim3(256), 0, stream>>>(pooled, W1, b1, h1);
    head2_kernel<<<dim3(1), dim3(256), 0, stream>>>(h1, W2, b2, (float*)d_out);
}

// Round 9
// 2883.687 us; speedup vs baseline: 3.9642x; 1.0819x over previous
//
#include <hip/hip_runtime.h>
#include <math.h>

// QRNN forward, round 7 schedule (resubmit x2; rounds 7-8 died at GPU
// acquisition, kernel never executed): conv GEMM K-step restructured — no
// redundant frag reads (24/step vs 48), A-half register pipeline (half1
// reads complete under half0 MFMA via compiler counted lgkmcnt), ONE
// __syncthreads per K-step. Numerics: bf16 hi/lo 3-product, fp32 accum.

#define B_   16
#define T_   1024
#define TP_  1026            // T + 2 zero-pad rows per batch (causal taps)
#define H_   1024
#define NL_  3
#define KW   3
#define N3H  3072
#define MTOT (B_ * T_)       // 16384
#define NSTEP 96             // KW * (H_/32)

// Global hi/lo-interleaved layout ("HL"): row stride 4096 B;
// k-group G (32 k) at G*128: [hi 32xbf16 (64B) | lo 32xbf16 (64B)].

typedef __attribute__((ext_vector_type(8))) __bf16 bfrag;     // MFMA A/B frag
typedef __attribute__((ext_vector_type(4))) float f32x4;      // MFMA C/D
typedef __attribute__((ext_vector_type(8))) unsigned short us8;
typedef __attribute__((ext_vector_type(4))) unsigned short us4;

typedef unsigned int __attribute__((address_space(1))) gu32;
typedef unsigned int __attribute__((address_space(3))) lu32;

static __device__ __forceinline__ void gl16(const void* g, void* l) {
    __builtin_amdgcn_global_load_lds((const gu32*)g, (lu32*)l, 16, 0, 0);
}
static __device__ __forceinline__ unsigned short f2bf(float x) {
    unsigned int u = __float_as_uint(x);
    u += 0x7fff + ((u >> 16) & 1);
    return (unsigned short)(u >> 16);
}
static __device__ __forceinline__ float bf2f(unsigned short h) {
    return __uint_as_float(((unsigned int)h) << 16);
}

// ------------------------------------------------- embedding gather + split
__global__ __launch_bounds__(128) void embed_split_kernel(
    const int* __restrict__ ids, const float* __restrict__ emb,
    char* __restrict__ XHL)
{
    const int tp = blockIdx.x;               // 0..TP_-1
    const int b  = blockIdx.y;
    const int tid = threadIdx.x;             // 0..127, 8 k each
    const int c0 = tid * 8;
    char* row = XHL + (size_t)(b * TP_ + tp) * 4096;
    char* hip_ = row + (tid >> 2) * 128 + (tid & 3) * 16;  // G = tid>>2
    if (tp < 2) {
        *(us8*)hip_ = (us8)0;
        *(us8*)(hip_ + 64) = (us8)0;
        return;
    }
    const int id = ids[b * T_ + tp - 2];
    const float* src = emb + (size_t)id * H_ + c0;
    us8 h, l;
#pragma unroll
    for (int j = 0; j < 8; ++j) {
        float x = src[j];
        unsigned short hh = f2bf(x);
        h[j] = hh;
        l[j] = f2bf(x - bf2f(hh));
    }
    *(us8*)hip_ = h;
    *(us8*)(hip_ + 64) = l;
}

// --------------------- W transpose + split: (KW,H,3H) -> HL[(KW,3H) rows][H]
__global__ __launch_bounds__(256) void wsplit_kernel(
    const float* __restrict__ W, char* __restrict__ WHL)
{
    __shared__ float t[32][33];
    const int kk = blockIdx.z;
    const int i0 = blockIdx.y * 32;          // k tile
    const int n0 = blockIdx.x * 32;          // n tile
    const int r = threadIdx.x >> 3;
    const int c = (threadIdx.x & 7) * 4;
    const float4 v = *(const float4*)(W + ((size_t)kk * H_ + i0 + r) * N3H + n0 + c);
    t[r][c] = v.x; t[r][c + 1] = v.y; t[r][c + 2] = v.z; t[r][c + 3] = v.w;
    __syncthreads();
    // out row = kk*N3H + n0 + r; group G = i0>>5; within-group k = c..c+3
    char* out = WHL + (size_t)(kk * N3H + n0 + r) * 4096 + (i0 >> 5) * 128 + c * 2;
    us4 h, l;
#pragma unroll
    for (int j = 0; j < 4; ++j) {
        float x = t[c + j][r];
        unsigned short hh = f2bf(x);
        h[j] = hh;
        l[j] = f2bf(x - bf2f(hh));
    }
    *(us4*)out = h;
    *(us4*)(out + 64) = l;
}

// ---------------- conv GEMM, 256x256 tile, pipelined single-barrier K-steps
__global__ __launch_bounds__(512, 2) void conv_gemm_pipe(
    const char* __restrict__ XHL, const char* __restrict__ WHL,
    const float* __restrict__ bias, float* __restrict__ ZFO)
{
    extern __shared__ char lds[];            // 2 bufs x (A 32KB | B 32KB)

    const int tid = threadIdx.x, lane = tid & 63, w = tid >> 6;
    const int wr = w >> 2, wc = w & 3;       // 2 x 4 waves

    // bijective XCD swizzle: nwg = 768 = 8 * 96
    const int id0 = blockIdx.y * gridDim.x + blockIdx.x;
    const int sw  = (id0 & 7) * 96 + (id0 >> 3);
    const int bx = sw % 12, by = sw / 12;
    const int m0 = by * 256, n0 = bx * 256;
    const int batch = m0 >> 10, t0 = m0 & 1023;

    // staging: thread covers LDS row (j*64 + tid>>3), chunk tid&7;
    // source chunk = dest chunk ^ (row&7), row&7 == (tid>>3)&7.
    const int rtid = tid >> 3;
    const int swz  = ((lane & 7) ^ (lane >> 3)) << 4;
    const char* Abase = XHL + (size_t)(batch * TP_ + t0) * 4096;

    // ds_read swizzled chunk offsets (read row&7 == lane&7)
    const int hsw = (((lane >> 4)) ^ (lane & 7)) << 4;
    const int lsw = (((lane >> 4) | 4) ^ (lane & 7)) << 4;
    const int arow = (wr * 128 + (lane & 15)) << 7;            // byte, A tile
    const int brow = ((wc * 64 + (lane & 15)) << 7) + 32768;   // byte, B tile

    f32x4 acc[8][4];
#pragma unroll
    for (int m = 0; m < 8; ++m)
#pragma unroll
        for (int n = 0; n < 4; ++n) acc[m][n] = (f32x4)0.f;

    // ---- staging helpers (4 x gl16 each: 64 rows x 128B per issue) ----
#define STAGE_A(bufb, kk, G)                                                  \
    {                                                                         \
        char* ldst = lds + ((bufb) << 16);                                    \
        const char* src = Abase + (size_t)((kk) + rtid) * 4096 + (G) * 128 + swz; \
        _Pragma("unroll")                                                     \
        for (int j = 0; j < 4; ++j)                                           \
            gl16(src + (size_t)j * (64 * 4096), ldst + j * 8192 + tid * 16);  \
    }
#define STAGE_B(bufb, kk, G)                                                  \
    {                                                                         \
        char* ldst = lds + ((bufb) << 16) + 32768;                            \
        const char* src = WHL + (size_t)((kk) * N3H + n0 + rtid) * 4096 + (G) * 128 + swz; \
        _Pragma("unroll")                                                     \
        for (int j = 0; j < 4; ++j)                                           \
            gl16(src + (size_t)j * (64 * 4096), ldst + j * 8192 + tid * 16);  \
    }

    // prologue: stage step 0 (syncthreads drains vmcnt + barrier)
    STAGE_A(0, 0, 0);
    STAGE_B(0, 0, 0);
    __syncthreads();

    for (int t = 0; t < NSTEP; ++t) {
        const int buf = t & 1;
        const char* L = lds + (buf << 16);
        const int tn = t + 1;
        const int kkn = tn >> 5, Gn = tn & 31;
        const bool more = (t < NSTEP - 1);

        // ---- issue ALL reads for this step (each frag read ONCE) ----
        bfrag ah[4], al[4], bh[4], bl[4], a2h[4], a2l[4];
#pragma unroll
        for (int m = 0; m < 4; ++m) {              // A half0: m-tiles 0..3
            const int ro = arow + (m << 11);
            ah[m] = *(const bfrag*)(L + ro + hsw);
            al[m] = *(const bfrag*)(L + ro + lsw);
        }
#pragma unroll
        for (int n = 0; n < 4; ++n) {              // B: all 4 n-tiles
            const int ro = brow + (n << 11);
            bh[n] = *(const bfrag*)(L + ro + hsw);
            bl[n] = *(const bfrag*)(L + ro + lsw);
        }
#pragma unroll
        for (int m = 0; m < 4; ++m) {              // A half1: m-tiles 4..7
            const int ro = arow + ((4 + m) << 11);
            a2h[m] = *(const bfrag*)(L + ro + hsw);
            a2l[m] = *(const bfrag*)(L + ro + lsw);
        }

        // ---- stage next step while reads/MFMA run ----
        if (more) { STAGE_A(buf ^ 1, kkn, Gn); STAGE_B(buf ^ 1, kkn, Gn); }

        __builtin_amdgcn_sched_barrier(0);   // keep issues above the MFMA body

        __builtin_amdgcn_s_setprio(1);
        // half0 MFMA (compiler emits counted lgkmcnt: a2 reads stay in flight)
#pragma unroll
        for (int m = 0; m < 4; ++m)
#pragma unroll
            for (int n = 0; n < 4; ++n) {
                f32x4 a0 = acc[m][n];
                a0 = __builtin_amdgcn_mfma_f32_16x16x32_bf16(ah[m], bh[n], a0, 0, 0, 0);
                a0 = __builtin_amdgcn_mfma_f32_16x16x32_bf16(ah[m], bl[n], a0, 0, 0, 0);
                a0 = __builtin_amdgcn_mfma_f32_16x16x32_bf16(al[m], bh[n], a0, 0, 0, 0);
                acc[m][n] = a0;
            }
        // half1 MFMA (a2 reads completed during half0)
#pragma unroll
        for (int m = 0; m < 4; ++m)
#pragma unroll
            for (int n = 0; n < 4; ++n) {
                f32x4 a0 = acc[4 + m][n];
                a0 = __builtin_amdgcn_mfma_f32_16x16x32_bf16(a2h[m], bh[n], a0, 0, 0, 0);
                a0 = __builtin_amdgcn_mfma_f32_16x16x32_bf16(a2h[m], bl[n], a0, 0, 0, 0);
                a0 = __builtin_amdgcn_mfma_f32_16x16x32_bf16(a2l[m], bh[n], a0, 0, 0, 0);
                acc[4 + m][n] = a0;
            }
        __builtin_amdgcn_s_setprio(0);

        __syncthreads();   // single per-step barrier: drains staging vmcnt
    }

    // epilogue: bias + activation, direct stores
    const int lcol = lane & 15, lrow = (lane >> 4) * 4;
#pragma unroll
    for (int n4 = 0; n4 < 4; ++n4) {
        const int col = n0 + wc * 64 + n4 * 16 + lcol;
        const float bs = bias[col];
        const int region = col >> 10;        // uniform across the 16 cols
#pragma unroll
        for (int m = 0; m < 8; ++m) {
            const int row = m0 + wr * 128 + m * 16 + lrow;
#pragma unroll
            for (int j = 0; j < 4; ++j) {
                float v = acc[m][n4][j] + bs;
                v = (region == 0) ? tanhf(v) : (1.f / (1.f + expf(-v)));
                ZFO[(size_t)(row + j) * N3H + col] = v;
            }
        }
    }
#undef STAGE_A
#undef STAGE_B
}

// ------------------------------------------------ fo_pool (in-place: h -> z-slot)
__global__ __launch_bounds__(256) void fo_scan_kernel(float* __restrict__ ZFO,
                                                      float* __restrict__ hidden,
                                                      int use_h0)
{
    const int id = blockIdx.x * 256 + threadIdx.x;   // 0..16383
    const int b = id >> 10, c = id & 1023;
    float h = use_h0 ? hidden[id] : 0.f;
    float* base = ZFO + (size_t)b * T_ * N3H + c;
    for (int t = 0; t < T_; t += 8) {
        float zv[8], fv[8], ov[8];
#pragma unroll
        for (int u = 0; u < 8; ++u) {
            float* p = base + (size_t)(t + u) * N3H;
            zv[u] = p[0]; fv[u] = p[H_]; ov[u] = p[2 * H_];
        }
#pragma unroll
        for (int u = 0; u < 8; ++u) {
            const float a  = ov[u] * fv[u];
            const float bb = ov[u] * (1.f - fv[u]) * zv[u];
            h = fmaf(a, h, bb);
            base[(size_t)(t + u) * N3H] = h;
        }
    }
    hidden[id] = h;
}

// ---------------------- LayerNorm + residual; emits fp32 x (f-slot) + HL X
__global__ __launch_bounds__(256) void ln_kernel(
    const float* __restrict__ Hs,        // h in ZFO z-slot, row stride N3H
    const float* __restrict__ g, const float* __restrict__ be,
    const float* __restrict__ skip,
    float* __restrict__ OutCur,          // LN out (fp32, stride H_)
    float* __restrict__ Xfin,            // x_next fp32 -> ZFO f-slot
    char* __restrict__ XHL,
    int add_skip)
{
    __shared__ float red[8];
    const int row = blockIdx.x;
    const int tid = threadIdx.x;

    const float4 v = *(const float4*)(Hs + (size_t)row * N3H + tid * 4);
    float s  = v.x + v.y + v.z + v.w;
    float s2 = v.x * v.x + v.y * v.y + v.z * v.z + v.w * v.w;
#pragma unroll
    for (int off = 32; off; off >>= 1) {
        s  += __shfl_down(s, off);
        s2 += __shfl_down(s2, off);
    }
    if ((tid & 63) == 0) { red[tid >> 6] = s; red[4 + (tid >> 6)] = s2; }
    __syncthreads();
    s  = red[0] + red[1] + red[2] + red[3];
    s2 = red[4] + red[5] + red[6] + red[7];

    const float mu  = s * (1.f / 1024.f);
    const float var = s2 * (1.f / 1024.f) - mu * mu;
    const float inv = 1.f / sqrtf(var + 1e-5f);

    const float4 gg = *(const float4*)(g  + tid * 4);
    const float4 bb = *(const float4*)(be + tid * 4);
    float4 o;
    o.x = (v.x - mu) * inv * gg.x + bb.x;
    o.y = (v.y - mu) * inv * gg.y + bb.y;
    o.z = (v.z - mu) * inv * gg.z + bb.z;
    o.w = (v.w - mu) * inv * gg.w + bb.w;
    *(float4*)(OutCur + (size_t)row * H_ + tid * 4) = o;

    float4 xn = o;
    if (add_skip) {
        const float4 sk = *(const float4*)(skip + (size_t)row * H_ + tid * 4);
        xn.x += sk.x; xn.y += sk.y; xn.z += sk.z; xn.w += sk.w;
    }
    *(float4*)(Xfin + (size_t)row * N3H + tid * 4) = xn;

    // split-bf16 X (HL layout) for next layer's GEMM
    const int b = row >> 10, t = row & 1023;
    char* xrow = XHL + (size_t)(b * TP_ + t + 2) * 4096
               + (tid >> 3) * 128 + (tid & 7) * 8;   // G = tid>>3, k off = (tid&7)*4
    const float xv[4] = {xn.x, xn.y, xn.z, xn.w};
    us4 hh, ll;
#pragma unroll
    for (int j = 0; j < 4; ++j) {
        unsigned short hb = f2bf(xv[j]);
        hh[j] = hb;
        ll[j] = f2bf(xv[j] - bf2f(hb));
    }
    *(us4*)xrow = hh;
    *(us4*)(xrow + 64) = ll;
}

// ---------------------------------------------------------------- mask/pool
__global__ __launch_bounds__(256) void lengths_kernel(const int* __restrict__ mask,
                                                      int* __restrict__ lengths) {
    __shared__ int red[4];
    const int b = blockIdx.x, tid = threadIdx.x;
    int s = 0;
    for (int k = tid; k < T_; k += 256) s += mask[b * T_ + k];
#pragma unroll
    for (int off = 32; off; off >>= 1) s += __shfl_down(s, off);
    if ((tid & 63) == 0) red[tid >> 6] = s;
    __syncthreads();
    if (tid == 0) lengths[b] = red[0] + red[1] + red[2] + red[3];
}

__global__ __launch_bounds__(256) void maxpool_kernel(const float* __restrict__ Xfin,
                                                      const int* __restrict__ lengths,
                                                      float* __restrict__ pooled) {
    const int id = blockIdx.x * 256 + threadIdx.x;
    const int b = id >> 10, c = id & 1023;
    const int len = lengths[b];
    const float* p = Xfin + (size_t)b * T_ * N3H + c;
    float m = -INFINITY;
    int t = 0;
    for (; t + 8 <= len; t += 8) {
#pragma unroll
        for (int u = 0; u < 8; ++u) m = fmaxf(m, p[(size_t)(t + u) * N3H]);
    }
    for (; t < len; ++t) m = fmaxf(m, p[(size_t)t * N3H]);
    pooled[id] = m;
}

// --------------------------------------------------------------------- head
__global__ __launch_bounds__(256) void head1_kernel(const float* __restrict__ pooled,
                                                    const float* __restrict__ W1,
                                                    const float* __restrict__ b1,
                                                    float* __restrict__ h1) {
    const int id = blockIdx.x * 256 + threadIdx.x;
    const int b = id >> 10, j = id & 1023;
    const float* pb = pooled + b * H_;
    float acc = 0.f;
    for (int i = 0; i < H_; i += 8) {
#pragma unroll
        for (int u = 0; u < 8; ++u)
            acc = fmaf(pb[i + u], W1[(size_t)(i + u) * H_ + j], acc);
    }
    h1[id] = fmaxf(acc + b1[j], 0.f);
}

__global__ __launch_bounds__(256) void head2_kernel(const float* __restrict__ h1,
                                                    const float* __restrict__ W2,
                                                    const float* __restrict__ b2,
                                                    float* __restrict__ out) {
    const int tid = threadIdx.x;
    const int oi = tid >> 3;
    const int seg = tid & 7;
    const int b = oi >> 1, jo = oi & 1;
    const float* hb = h1 + b * H_;
    float acc = 0.f;
    const int i0 = seg * 128;
    for (int i = i0; i < i0 + 128; ++i)
        acc = fmaf(hb[i], W2[i * 2 + jo], acc);
    acc += __shfl_down(acc, 4);
    acc += __shfl_down(acc, 2);
    acc += __shfl_down(acc, 1);
    if (seg == 0) out[oi] = acc + b2[jo];
}

// ------------------------------------------------------------------- launch
extern "C" void kernel_launch(void* const* d_in, const int* in_sizes, int n_in,
                              void* d_out, int out_size, void* d_ws, size_t ws_size,
                              hipStream_t stream) {
    const int*   input_ids = (const int*)d_in[0];
    const int*   attn_mask = (const int*)d_in[1];
    const float* emb   = (const float*)d_in[2];
    const float* convW = (const float*)d_in[3];
    const float* convb = (const float*)d_in[4];
    const float* gamma = (const float*)d_in[5];
    const float* beta  = (const float*)d_in[6];
    const float* W1    = (const float*)d_in[7];
    const float* b1    = (const float*)d_in[8];
    const float* W2    = (const float*)d_in[9];
    const float* b2    = (const float*)d_in[10];

    // workspace (~441 MB, same as round 2)
    float* ZFO  = (float*)d_ws;                                  // MTOT*N3H f32
    float* Out0 = ZFO  + (size_t)MTOT * N3H;
    float* Out1 = Out0 + (size_t)MTOT * H_;
    char*  XHL  = (char*)(Out1 + (size_t)MTOT * H_);             // B*TP*4096 B
    char*  WHL  = XHL + (size_t)B_ * TP_ * 4096;                 // KW*N3H*4096 B
    float* hidden  = (float*)(WHL + (size_t)KW * N3H * 4096);
    float* pooled  = hidden + (size_t)B_ * H_;
    float* h1      = pooled + (size_t)B_ * H_;
    int*   lengths = (int*)(h1 + (size_t)B_ * H_);

    hipFuncSetAttribute((const void*)conv_gemm_pipe,
                        hipFuncAttributeMaxDynamicSharedMemorySize, 131072);

    embed_split_kernel<<<dim3(TP_, B_), 128, 0, stream>>>(input_ids, emb, XHL);

    const float* skipPrev = nullptr;
    float* outs[2] = {Out0, Out1};
    for (int l = 0; l < NL_; ++l) {
        wsplit_kernel<<<dim3(N3H / 32, H_ / 32, KW), 256, 0, stream>>>(
            convW + (size_t)l * KW * H_ * N3H, WHL);
        conv_gemm_pipe<<<dim3(12, 64), 512, 131072, stream>>>(
            XHL, WHL, convb + (size_t)l * N3H, ZFO);
        fo_scan_kernel<<<dim3(64), dim3(256), 0, stream>>>(ZFO, hidden, l > 0 ? 1 : 0);
        ln_kernel<<<dim3(MTOT), dim3(256), 0, stream>>>(
            ZFO, gamma + (size_t)l * H_, beta + (size_t)l * H_,
            skipPrev, outs[l & 1], ZFO + H_, XHL, l > 0 ? 1 : 0);
        skipPrev = outs[l & 1];
    }

    lengths_kernel<<<dim3(B_), dim3(256), 0, stream>>>(attn_mask, lengths);
    maxpool_kernel<<<dim3(64), dim3(256), 0, stream>>>(ZFO + H_, lengths, pooled);
    head1_kernel<<<dim3(64), dim3(256), 0, stream>>>(pooled, W1, b1, h1);
    head2_kernel<<<dim3(1), dim3(256), 0, stream>>>(h1, W2, b2, (float*)d_out);
}